// Round 6
// baseline (583.284 us; speedup 1.0000x reference)
//
#include <hip/hip_runtime.h>
#include <math.h>

#define SEQ 4096
#define DM  1024
#define NH  16
#define DH  64

typedef _Float16 h16;
typedef __attribute__((ext_vector_type(4))) _Float16 h16x4;
typedef __attribute__((ext_vector_type(8))) _Float16 h16x8;
typedef __attribute__((ext_vector_type(4))) float f32x4;

__device__ __forceinline__ h16x4 cvt4(f32x4 v) {
    h16x4 o = { (h16)v.x, (h16)v.y, (h16)v.z, (h16)v.w };
    return o;
}

// ---------------------------------------------------------------------------
// MFMA GEMM: C[M][N] = A[M][K] @ B[N][K]^T, fp32 accumulate.
// Tile 64(M)x128(N), BK=32, 256 thr = 4 waves (2x2 of 32x64), grid 512 blocks
// = 2 blocks/CU. LDS double-buffered + 2-slab register prefetch.
// B is always fp32 (weights), converted to h16 during staging.
// AF32=1: A fp32 (x). AF32=0: A h16 (attention output).
// OUT: 0 = h16 [M][N] (*escale); 1 = h16 transposed [N][M]; 2 = f32 [M][N].
// GST=40 h16 (20 dw, 20*l15+4*lq mod 32 balanced -> conflict-free b128 frags).
// ---------------------------------------------------------------------------
#define GST 40

template<int OUT, int AF32>
__global__ __launch_bounds__(256, 2) void gemm_mfma(const void* __restrict__ Av,
                                                    const float* __restrict__ B,
                                                    void* __restrict__ Cv,
                                                    int M, int N, int K, float escale) {
    __shared__ h16 As[2][64 * GST];
    __shared__ h16 Bs[2][128 * GST];

    const int t    = threadIdx.x;
    const int lane = t & 63;
    const int w    = t >> 6;
    const int wm   = (w >> 1) * 32;
    const int wn   = (w & 1) * 64;
    const int l15  = lane & 15;
    const int lq   = lane >> 4;
    const int lq8  = lq * 8;
    const int m0   = blockIdx.y * 64;
    const int n0   = blockIdx.x * 128;

    const int srow = t >> 3;          // 0..31
    const int sc4  = (t & 7) * 4;     // fp32 col within BK
    const int arow = t >> 2;          // 0..63 (h16-A path)
    const int ac8  = (t & 3) * 8;     // h16 col within BK

    const float* Af = (const float*)Av;
    const h16*   Ah = (const h16*)Av;

    f32x4 acc[2][4] = {};

    // 2-deep prefetch registers
    f32x4 a0[2], a1[2], b0[4], b1[4];
    h16x8 ha0, ha1;

    if (AF32) {
        a0[0] = *(const f32x4*)(Af + (size_t)(m0 + srow) * K + sc4);
        a0[1] = *(const f32x4*)(Af + (size_t)(m0 + 32 + srow) * K + sc4);
        a1[0] = *(const f32x4*)(Af + (size_t)(m0 + srow) * K + 32 + sc4);
        a1[1] = *(const f32x4*)(Af + (size_t)(m0 + 32 + srow) * K + 32 + sc4);
    } else {
        ha0 = *(const h16x8*)(Ah + (size_t)(m0 + arow) * K + ac8);
        ha1 = *(const h16x8*)(Ah + (size_t)(m0 + arow) * K + 32 + ac8);
    }
    #pragma unroll
    for (int c = 0; c < 4; ++c) {
        b0[c] = *(const f32x4*)(B + (size_t)(n0 + srow + 32 * c) * K + sc4);
        b1[c] = *(const f32x4*)(B + (size_t)(n0 + srow + 32 * c) * K + 32 + sc4);
    }

    int p = 0;
    for (int k0 = 0; k0 < K; k0 += 32) {
        // ---- store slab k0 into buf p (convert fp32->h16) ----
        if (AF32) {
            *(h16x4*)&As[p][srow * GST + sc4]        = cvt4(a0[0]);
            *(h16x4*)&As[p][(32 + srow) * GST + sc4] = cvt4(a0[1]);
        } else {
            *(h16x8*)&As[p][arow * GST + ac8] = ha0;
        }
        #pragma unroll
        for (int c = 0; c < 4; ++c)
            *(h16x4*)&Bs[p][(srow + 32 * c) * GST + sc4] = cvt4(b0[c]);
        __syncthreads();

        // ---- shift pipeline, prefetch slab k0+64 ----
        if (AF32) { a0[0] = a1[0]; a0[1] = a1[1]; } else { ha0 = ha1; }
        #pragma unroll
        for (int c = 0; c < 4; ++c) b0[c] = b1[c];
        if (k0 + 64 < K) {
            if (AF32) {
                a1[0] = *(const f32x4*)(Af + (size_t)(m0 + srow) * K + k0 + 64 + sc4);
                a1[1] = *(const f32x4*)(Af + (size_t)(m0 + 32 + srow) * K + k0 + 64 + sc4);
            } else {
                ha1 = *(const h16x8*)(Ah + (size_t)(m0 + arow) * K + k0 + 64 + ac8);
            }
            #pragma unroll
            for (int c = 0; c < 4; ++c)
                b1[c] = *(const f32x4*)(B + (size_t)(n0 + srow + 32 * c) * K + k0 + 64 + sc4);
        }

        // ---- compute from buf p ----
        h16x8 af[2], bf[4];
        #pragma unroll
        for (int i = 0; i < 2; ++i)
            af[i] = *(const h16x8*)&As[p][(wm + i * 16 + l15) * GST + lq8];
        #pragma unroll
        for (int j = 0; j < 4; ++j)
            bf[j] = *(const h16x8*)&Bs[p][(wn + j * 16 + l15) * GST + lq8];
        #pragma unroll
        for (int i = 0; i < 2; ++i)
            #pragma unroll
            for (int j = 0; j < 4; ++j)
                acc[i][j] = __builtin_amdgcn_mfma_f32_16x16x32_f16(af[i], bf[j], acc[i][j], 0, 0, 0);
        p ^= 1;
    }

    // C/D layout: col = lane&15, row = (lane>>4)*4 + r
    const int cr = wm + lq * 4;
    const int cc = wn + l15;
    #pragma unroll
    for (int i = 0; i < 2; ++i)
        #pragma unroll
        for (int j = 0; j < 4; ++j) {
            const int gm0 = m0 + cr + i * 16;
            const int gn  = n0 + cc + j * 16;
            if (OUT == 1) {
                h16x4 v = { (h16)(acc[i][j][0] * escale), (h16)(acc[i][j][1] * escale),
                            (h16)(acc[i][j][2] * escale), (h16)(acc[i][j][3] * escale) };
                *(h16x4*)((h16*)Cv + (size_t)gn * M + gm0) = v;
            } else {
                #pragma unroll
                for (int r = 0; r < 4; ++r) {
                    if (OUT == 2) ((float*)Cv)[(size_t)(gm0 + r) * N + gn] = acc[i][j][r] * escale;
                    else          ((h16*)Cv)[(size_t)(gm0 + r) * N + gn] = (h16)(acc[i][j][r] * escale);
                }
            }
        }
}

// ---------------------------------------------------------------------------
// MFMA flash attention (causal), S^T formulation, exp2 domain.
// Q is pre-scaled by (1/sqrt(DH))*log2(e) in the Q-GEMM epilogue, so softmax
// is pure exp2 with no per-entry multiply. Causal mask applied only on the
// (block-uniform) diagonal iteration.
// Block = (pair of q-tiles {qA, 63-qA}, head): 65 tile-steps/block, grid 512.
// Single-buffered K/V + Ps[2] at AST=72 -> 36 KB LDS -> 4 blocks/CU.
// AST=72 h16 = 36 dw == 4 (mod 32): all frag reads/stores bank-balanced.
// ---------------------------------------------------------------------------
#define AST 72

__device__ __forceinline__ void tile_softmax(f32x4 s[4], float& m_st, float& l_st,
                                             f32x4 o[4], h16* ps_row, bool diag,
                                             int q_loc, int lq) {
    if (diag) {   // block-uniform branch: only on the diagonal tile
        #pragma unroll
        for (int jj = 0; jj < 4; ++jj)
            #pragma unroll
            for (int r = 0; r < 4; ++r)
                if ((jj * 16 + lq * 4 + r) > q_loc) s[jj][r] = -1e30f;
    }
    float mx = m_st;
    #pragma unroll
    for (int jj = 0; jj < 4; ++jj)
        #pragma unroll
        for (int r = 0; r < 4; ++r)
            mx = fmaxf(mx, s[jj][r]);
    mx = fmaxf(mx, __shfl_xor(mx, 16, 64));
    mx = fmaxf(mx, __shfl_xor(mx, 32, 64));
    const float alpha = exp2f(m_st - mx);
    m_st = mx;
    float sum = 0.0f;
    #pragma unroll
    for (int jj = 0; jj < 4; ++jj) {
        const float p0 = exp2f(s[jj][0] - mx);
        const float p1 = exp2f(s[jj][1] - mx);
        const float p2 = exp2f(s[jj][2] - mx);
        const float p3 = exp2f(s[jj][3] - mx);
        sum += (p0 + p1) + (p2 + p3);
        h16x4 pk = { (h16)p0, (h16)p1, (h16)p2, (h16)p3 };
        *(h16x4*)(ps_row + jj * 16 + lq * 4) = pk;
    }
    sum += __shfl_xor(sum, 16, 64);
    sum += __shfl_xor(sum, 32, 64);
    l_st = l_st * alpha + sum;
    #pragma unroll
    for (int jj = 0; jj < 4; ++jj)
        #pragma unroll
        for (int r = 0; r < 4; ++r)
            o[jj][r] *= alpha;
}

__global__ __launch_bounds__(256, 4) void flash_attn_mfma(
        const h16* __restrict__ Qg, const h16* __restrict__ Kg,
        const h16* __restrict__ Vt, h16* __restrict__ Og) {
    __shared__ h16 Ks[64 * AST];      // [k_local][d]
    __shared__ h16 Vs[64 * AST];      // [d][k_local]
    __shared__ h16 Ps[2][64 * AST];   // [tile][q][k]

    const int qA   = blockIdx.x;          // 0..31
    const int qB   = 63 - qA;             // 32..63
    const int hh   = blockIdx.y;
    const int t    = threadIdx.x;
    const int lane = t & 63;
    const int w    = t >> 6;
    const int l15  = lane & 15;
    const int lq   = lane >> 4;
    const int lq8  = lq * 8;
    const int hc   = hh * DH;
    const int q_loc = w * 16 + l15;

    const int r1 = t >> 3;                // 0..31
    const int r2 = r1 + 32;
    const int c1 = (t & 7) * 8;

    // stage Q(A) into Ks, Q(B) into Vs (reused before loop overwrites)
    {
        const int qa0 = qA * 64, qb0 = qB * 64;
        *(h16x8*)&Ks[r1 * AST + c1] = *(const h16x8*)(Qg + (size_t)(qa0 + r1) * DM + hc + c1);
        *(h16x8*)&Ks[r2 * AST + c1] = *(const h16x8*)(Qg + (size_t)(qa0 + r2) * DM + hc + c1);
        *(h16x8*)&Vs[r1 * AST + c1] = *(const h16x8*)(Qg + (size_t)(qb0 + r1) * DM + hc + c1);
        *(h16x8*)&Vs[r2 * AST + c1] = *(const h16x8*)(Qg + (size_t)(qb0 + r2) * DM + hc + c1);
    }
    // preload kt=0 K/V tile into regs
    h16x8 kv1 = *(const h16x8*)(Kg + (size_t)(r1) * DM + hc + c1);
    h16x8 kv2 = *(const h16x8*)(Kg + (size_t)(r2) * DM + hc + c1);
    h16x8 vv1 = *(const h16x8*)(Vt + (size_t)(hc + r1) * SEQ + c1);
    h16x8 vv2 = *(const h16x8*)(Vt + (size_t)(hc + r2) * SEQ + c1);

    __syncthreads();
    h16x8 qfA[2], qfB[2];
    qfA[0] = *(const h16x8*)&Ks[q_loc * AST + lq8];
    qfA[1] = *(const h16x8*)&Ks[q_loc * AST + 32 + lq8];
    qfB[0] = *(const h16x8*)&Vs[q_loc * AST + lq8];
    qfB[1] = *(const h16x8*)&Vs[q_loc * AST + 32 + lq8];

    float mA = -1e30f, lA = 0.0f, mB = -1e30f, lB = 0.0f;
    f32x4 oA[4] = {}, oB[4] = {};
    h16* const psA = &Ps[0][(size_t)q_loc * AST];
    h16* const psB = &Ps[1][(size_t)q_loc * AST];

    for (int kt = 0; kt <= qB; ++kt) {
        __syncthreads();   // prior iter's (and Q-frag) LDS reads drained
        *(h16x8*)&Ks[r1 * AST + c1] = kv1;
        *(h16x8*)&Ks[r2 * AST + c1] = kv2;
        *(h16x8*)&Vs[r1 * AST + c1] = vv1;
        *(h16x8*)&Vs[r2 * AST + c1] = vv2;
        __syncthreads();
        if (kt < qB) {   // prefetch next K/V tile (overlaps full compute phase)
            const int k0n = (kt + 1) * 64;
            kv1 = *(const h16x8*)(Kg + (size_t)(k0n + r1) * DM + hc + c1);
            kv2 = *(const h16x8*)(Kg + (size_t)(k0n + r2) * DM + hc + c1);
            vv1 = *(const h16x8*)(Vt + (size_t)(hc + r1) * SEQ + k0n + c1);
            vv2 = *(const h16x8*)(Vt + (size_t)(hc + r2) * SEQ + k0n + c1);
        }
        const bool doA = (kt <= qA);

        // ---- S^T = K Q^T : K-frags read once, shared by both tiles ----
        f32x4 sA[4] = {}, sB[4] = {};
        #pragma unroll
        for (int kc = 0; kc < 2; ++kc)
            #pragma unroll
            for (int jj = 0; jj < 4; ++jj) {
                const h16x8 kf = *(const h16x8*)&Ks[(jj * 16 + l15) * AST + kc * 32 + lq8];
                if (doA) sA[jj] = __builtin_amdgcn_mfma_f32_16x16x32_f16(kf, qfA[kc], sA[jj], 0, 0, 0);
                sB[jj] = __builtin_amdgcn_mfma_f32_16x16x32_f16(kf, qfB[kc], sB[jj], 0, 0, 0);
            }

        if (doA) tile_softmax(sA, mA, lA, oA, psA, kt == qA, q_loc, lq);
        tile_softmax(sB, mB, lB, oB, psB, kt == qB, q_loc, lq);

        // wave-local LDS round-trip for P^T (own 16-row band only)
        asm volatile("s_waitcnt lgkmcnt(0)" ::: "memory");
        h16x8 pfA[2], pfB[2];
        if (doA) {
            pfA[0] = *(const h16x8*)(psA + lq8);
            pfA[1] = *(const h16x8*)(psA + 32 + lq8);
        }
        pfB[0] = *(const h16x8*)(psB + lq8);
        pfB[1] = *(const h16x8*)(psB + 32 + lq8);

        // ---- O^T += V^T P^T : V-frags read once, shared by both tiles ----
        #pragma unroll
        for (int kc = 0; kc < 2; ++kc)
            #pragma unroll
            for (int jj = 0; jj < 4; ++jj) {
                const h16x8 vf = *(const h16x8*)&Vs[(jj * 16 + l15) * AST + kc * 32 + lq8];
                if (doA) oA[jj] = __builtin_amdgcn_mfma_f32_16x16x32_f16(vf, pfA[kc], oA[jj], 0, 0, 0);
                oB[jj] = __builtin_amdgcn_mfma_f32_16x16x32_f16(vf, pfB[kc], oB[jj], 0, 0, 0);
            }
    }

    // ---- epilogue: O = O^T / l ----
    {
        const float il = 1.0f / lA;
        const size_t qg = (size_t)(qA * 64 + q_loc) * DM + hc;
        #pragma unroll
        for (int jj = 0; jj < 4; ++jj) {
            h16x4 ov = { (h16)(oA[jj][0] * il), (h16)(oA[jj][1] * il),
                         (h16)(oA[jj][2] * il), (h16)(oA[jj][3] * il) };
            *(h16x4*)(Og + qg + jj * 16 + lq * 4) = ov;
        }
    }
    {
        const float il = 1.0f / lB;
        const size_t qg = (size_t)(qB * 64 + q_loc) * DM + hc;
        #pragma unroll
        for (int jj = 0; jj < 4; ++jj) {
            h16x4 ov = { (h16)(oB[jj][0] * il), (h16)(oB[jj][1] * il),
                         (h16)(oB[jj][2] * il), (h16)(oB[jj][3] * il) };
            *(h16x4*)(Og + qg + jj * 16 + lq * 4) = ov;
        }
    }
}

// ---------------------------------------------------------------------------
extern "C" void kernel_launch(void* const* d_in, const int* in_sizes, int n_in,
                              void* d_out, int out_size, void* d_ws, size_t ws_size,
                              hipStream_t stream) {
    const float* x  = (const float*)d_in[0];
    const float* Wq = (const float*)d_in[1];
    const float* Wk = (const float*)d_in[2];
    const float* Wv = (const float*)d_in[3];
    const float* Wo = (const float*)d_in[4];
    float* out = (float*)d_out;

    const size_t SD = (size_t)SEQ * DM;   // 4M

    h16* Qh  = (h16*)d_ws;
    h16* Kh  = Qh + SD;
    h16* Vth = Kh + SD;     // transposed: [DM][SEQ]
    h16* AOh = Vth + SD;

    const dim3 blk(256);
    const dim3 gg(DM / 128, SEQ / 64);   // (8, 64) = 512 blocks

    // Q pre-scaled by 1/sqrt(DH) * log2(e) for the exp2-domain softmax
    const float SCL = 0.125f * 1.44269504088896340736f;

    gemm_mfma<0, 1><<<gg, blk, 0, stream>>>(x, Wq, Qh,  SEQ, DM, DM, SCL);
    gemm_mfma<0, 1><<<gg, blk, 0, stream>>>(x, Wk, Kh,  SEQ, DM, DM, 1.0f);
    gemm_mfma<1, 1><<<gg, blk, 0, stream>>>(x, Wv, Vth, SEQ, DM, DM, 1.0f);

    flash_attn_mfma<<<dim3(32, NH), blk, 0, stream>>>(Qh, Kh, Vth, AOh);

    gemm_mfma<2, 0><<<gg, blk, 0, stream>>>(AOh, Wo, out, SEQ, DM, DM, 1.0f);
}

// Round 7
// 263.456 us; speedup vs baseline: 2.2140x; 2.2140x over previous
//
#include <hip/hip_runtime.h>
#include <math.h>

#define SEQ 4096
#define DM  1024
#define NH  16
#define DH  64

typedef _Float16 h16;
typedef __attribute__((ext_vector_type(4))) _Float16 h16x4;
typedef __attribute__((ext_vector_type(8))) _Float16 h16x8;
typedef __attribute__((ext_vector_type(4))) float f32x4;

// ---------------------------------------------------------------------------
// fp32 -> fp16 conversion, vectorized
// ---------------------------------------------------------------------------
__global__ __launch_bounds__(256) void cvt_f32_f16(const float* __restrict__ in,
                                                   h16* __restrict__ out, int n4) {
    const int i = blockIdx.x * 256 + threadIdx.x;
    if (i < n4) {
        const float4 v = ((const float4*)in)[i];
        h16x4 o = { (h16)v.x, (h16)v.y, (h16)v.z, (h16)v.w };
        ((h16x4*)out)[i] = o;
    }
}

// ---------------------------------------------------------------------------
// Fused QKV GEMM: for z in {0,1,2}: C = x @ W{q,k,v}^T (h16 in, fp32 acc).
// z=0 -> Qh [S][D] * SCL ; z=1 -> Kh [S][D] ; z=2 -> Vth [D][S] (transposed).
// Tile 64(M)x128(N), BK=32, 256 thr = 4 waves (2x2 of 32x64).
// Double-buffered LDS (1 barrier/iter) + register prefetch. Grid (8,64,3).
// GST=40 h16: frag b128 reads bank-balanced (40dw*l15 mod 32 = 8*l15 -> 2-way,
// free per m136).
// ---------------------------------------------------------------------------
#define GST 40

__global__ __launch_bounds__(256, 2) void gemm_qkv(const h16* __restrict__ xh,
                                                   const h16* __restrict__ Wq,
                                                   const h16* __restrict__ Wk,
                                                   const h16* __restrict__ Wv,
                                                   h16* __restrict__ Qh,
                                                   h16* __restrict__ Kh,
                                                   h16* __restrict__ Vth,
                                                   float scl) {
    __shared__ h16 As[2][64 * GST];
    __shared__ h16 Bs[2][128 * GST];

    const int z    = blockIdx.z;
    const h16* B   = (z == 0) ? Wq : (z == 1) ? Wk : Wv;
    const int t    = threadIdx.x;
    const int lane = t & 63;
    const int w    = t >> 6;
    const int wm   = (w >> 1) * 32;
    const int wn   = (w & 1) * 64;
    const int l15  = lane & 15;
    const int lq   = lane >> 4;
    const int lq8  = lq * 8;
    const int m0   = blockIdx.y * 64;
    const int n0   = blockIdx.x * 128;
    const int K    = DM, M = SEQ, N = DM;

    const int arow = t >> 2;          // 0..63
    const int ac8  = (t & 3) * 8;     // 0,8,16,24

    f32x4 acc[2][4] = {};

    const h16* pA  = xh + (size_t)(m0 + arow) * K + ac8;
    const h16* pB0 = B + (size_t)(n0 + arow) * K + ac8;
    const h16* pB1 = B + (size_t)(n0 + 64 + arow) * K + ac8;

    h16x8 ra = *(const h16x8*)pA;
    h16x8 rb0 = *(const h16x8*)pB0;
    h16x8 rb1 = *(const h16x8*)pB1;

    for (int k0 = 0; k0 < K; k0 += 32) {
        const int p = (k0 >> 5) & 1;
        *(h16x8*)&As[p][arow * GST + ac8]        = ra;
        *(h16x8*)&Bs[p][arow * GST + ac8]        = rb0;
        *(h16x8*)&Bs[p][(64 + arow) * GST + ac8] = rb1;
        __syncthreads();
        if (k0 + 32 < K) {
            ra  = *(const h16x8*)(pA + k0 + 32);
            rb0 = *(const h16x8*)(pB0 + k0 + 32);
            rb1 = *(const h16x8*)(pB1 + k0 + 32);
        }
        h16x8 af[2], bf[4];
        #pragma unroll
        for (int i = 0; i < 2; ++i)
            af[i] = *(const h16x8*)&As[p][(wm + i * 16 + l15) * GST + lq8];
        #pragma unroll
        for (int j = 0; j < 4; ++j)
            bf[j] = *(const h16x8*)&Bs[p][(wn + j * 16 + l15) * GST + lq8];
        #pragma unroll
        for (int i = 0; i < 2; ++i)
            #pragma unroll
            for (int j = 0; j < 4; ++j)
                acc[i][j] = __builtin_amdgcn_mfma_f32_16x16x32_f16(af[i], bf[j], acc[i][j], 0, 0, 0);
    }

    // C/D layout: col = lane&15, row = (lane>>4)*4 + r
    const int cr = wm + lq * 4;
    const int cc = wn + l15;
    if (z == 2) {   // transposed h16 [N][M] (V^T)
        #pragma unroll
        for (int i = 0; i < 2; ++i)
            #pragma unroll
            for (int j = 0; j < 4; ++j) {
                const int gm0 = m0 + cr + i * 16;
                const int gn  = n0 + cc + j * 16;
                h16x4 v = { (h16)acc[i][j][0], (h16)acc[i][j][1],
                            (h16)acc[i][j][2], (h16)acc[i][j][3] };
                *(h16x4*)(Vth + (size_t)gn * M + gm0) = v;
            }
    } else {
        h16* Og = (z == 0) ? Qh : Kh;
        const float e = (z == 0) ? scl : 1.0f;
        #pragma unroll
        for (int i = 0; i < 2; ++i)
            #pragma unroll
            for (int j = 0; j < 4; ++j)
                #pragma unroll
                for (int r = 0; r < 4; ++r) {
                    const int gm = m0 + cr + i * 16 + r;
                    const int gn = n0 + cc + j * 16;
                    Og[(size_t)gm * N + gn] = (h16)(acc[i][j][r] * e);
                }
    }
}

// ---------------------------------------------------------------------------
// Output GEMM: out[M][N] (f32) = AO[M][K] (h16) @ Wo[N][K]^T (h16).
// Same structure as gemm_qkv.
// ---------------------------------------------------------------------------
__global__ __launch_bounds__(256, 2) void gemm_out(const h16* __restrict__ A,
                                                   const h16* __restrict__ B,
                                                   float* __restrict__ C) {
    __shared__ h16 As[2][64 * GST];
    __shared__ h16 Bs[2][128 * GST];

    const int t    = threadIdx.x;
    const int lane = t & 63;
    const int w    = t >> 6;
    const int wm   = (w >> 1) * 32;
    const int wn   = (w & 1) * 64;
    const int l15  = lane & 15;
    const int lq   = lane >> 4;
    const int lq8  = lq * 8;
    const int m0   = blockIdx.y * 64;
    const int n0   = blockIdx.x * 128;
    const int K    = DM, N = DM;

    const int arow = t >> 2;
    const int ac8  = (t & 3) * 8;

    f32x4 acc[2][4] = {};

    const h16* pA  = A + (size_t)(m0 + arow) * K + ac8;
    const h16* pB0 = B + (size_t)(n0 + arow) * K + ac8;
    const h16* pB1 = B + (size_t)(n0 + 64 + arow) * K + ac8;

    h16x8 ra = *(const h16x8*)pA;
    h16x8 rb0 = *(const h16x8*)pB0;
    h16x8 rb1 = *(const h16x8*)pB1;

    for (int k0 = 0; k0 < K; k0 += 32) {
        const int p = (k0 >> 5) & 1;
        *(h16x8*)&As[p][arow * GST + ac8]        = ra;
        *(h16x8*)&Bs[p][arow * GST + ac8]        = rb0;
        *(h16x8*)&Bs[p][(64 + arow) * GST + ac8] = rb1;
        __syncthreads();
        if (k0 + 32 < K) {
            ra  = *(const h16x8*)(pA + k0 + 32);
            rb0 = *(const h16x8*)(pB0 + k0 + 32);
            rb1 = *(const h16x8*)(pB1 + k0 + 32);
        }
        h16x8 af[2], bf[4];
        #pragma unroll
        for (int i = 0; i < 2; ++i)
            af[i] = *(const h16x8*)&As[p][(wm + i * 16 + l15) * GST + lq8];
        #pragma unroll
        for (int j = 0; j < 4; ++j)
            bf[j] = *(const h16x8*)&Bs[p][(wn + j * 16 + l15) * GST + lq8];
        #pragma unroll
        for (int i = 0; i < 2; ++i)
            #pragma unroll
            for (int j = 0; j < 4; ++j)
                acc[i][j] = __builtin_amdgcn_mfma_f32_16x16x32_f16(af[i], bf[j], acc[i][j], 0, 0, 0);
    }

    const int cr = wm + lq * 4;
    const int cc = wn + l15;
    #pragma unroll
    for (int i = 0; i < 2; ++i)
        #pragma unroll
        for (int j = 0; j < 4; ++j)
            #pragma unroll
            for (int r = 0; r < 4; ++r)
                C[(size_t)(m0 + cr + i * 16 + r) * N + n0 + cc + j * 16] = acc[i][j][r];
}

// ---------------------------------------------------------------------------
// MFMA flash attention (causal), S^T formulation, exp2 domain.
// Q pre-scaled by (1/sqrt(DH))*log2(e) in the Q-GEMM epilogue.
// Block = (pair of q-tiles {qA, 63-qA}, head): 65 tile-steps/block, grid 512.
// Double-buffered K/V (1 barrier/iter). AST=72 -> frag b128 reads conflict-
// free (stride 36 dw: bank start 4*((l15+q) mod 8) covers all groups evenly).
// LDS 55.3 KB -> 2 blocks/CU; launch_bounds(256,2) -> no spills (~92 VGPR).
// ---------------------------------------------------------------------------
#define AST 72

__device__ __forceinline__ void tile_softmax(f32x4 s[4], float& m_st, float& l_st,
                                             f32x4 o[4], h16* ps_row, bool diag,
                                             int q_loc, int lq) {
    if (diag) {   // block-uniform branch: only on the diagonal tile
        #pragma unroll
        for (int jj = 0; jj < 4; ++jj)
            #pragma unroll
            for (int r = 0; r < 4; ++r)
                if ((jj * 16 + lq * 4 + r) > q_loc) s[jj][r] = -1e30f;
    }
    float mx = m_st;
    #pragma unroll
    for (int jj = 0; jj < 4; ++jj)
        #pragma unroll
        for (int r = 0; r < 4; ++r)
            mx = fmaxf(mx, s[jj][r]);
    mx = fmaxf(mx, __shfl_xor(mx, 16, 64));
    mx = fmaxf(mx, __shfl_xor(mx, 32, 64));
    const float alpha = exp2f(m_st - mx);
    m_st = mx;
    float sum = 0.0f;
    #pragma unroll
    for (int jj = 0; jj < 4; ++jj) {
        const float p0 = exp2f(s[jj][0] - mx);
        const float p1 = exp2f(s[jj][1] - mx);
        const float p2 = exp2f(s[jj][2] - mx);
        const float p3 = exp2f(s[jj][3] - mx);
        sum += (p0 + p1) + (p2 + p3);
        h16x4 pk = { (h16)p0, (h16)p1, (h16)p2, (h16)p3 };
        *(h16x4*)(ps_row + jj * 16 + lq * 4) = pk;
    }
    sum += __shfl_xor(sum, 16, 64);
    sum += __shfl_xor(sum, 32, 64);
    l_st = l_st * alpha + sum;
    #pragma unroll
    for (int jj = 0; jj < 4; ++jj)
        #pragma unroll
        for (int r = 0; r < 4; ++r)
            o[jj][r] *= alpha;
}

__global__ __launch_bounds__(256, 2) void flash_attn_mfma(
        const h16* __restrict__ Qg, const h16* __restrict__ Kg,
        const h16* __restrict__ Vt, h16* __restrict__ Og) {
    __shared__ h16 Ks[2][64 * AST];   // [k_local][d]
    __shared__ h16 Vs[2][64 * AST];   // [d][k_local]
    __shared__ h16 Ps[2][64 * AST];   // [tile][q][k]

    const int qA   = blockIdx.x;          // 0..31
    const int qB   = 63 - qA;             // 32..63
    const int hh   = blockIdx.y;
    const int t    = threadIdx.x;
    const int lane = t & 63;
    const int w    = t >> 6;
    const int l15  = lane & 15;
    const int lq   = lane >> 4;
    const int lq8  = lq * 8;
    const int hc   = hh * DH;
    const int q_loc = w * 16 + l15;

    const int r1 = t >> 3;                // 0..31
    const int r2 = r1 + 32;
    const int c1 = (t & 7) * 8;

    // stage Q(A) into Ks[0], Q(B) into Vs[0] (consumed before loop overwrites)
    {
        const int qa0 = qA * 64, qb0 = qB * 64;
        *(h16x8*)&Ks[0][r1 * AST + c1] = *(const h16x8*)(Qg + (size_t)(qa0 + r1) * DM + hc + c1);
        *(h16x8*)&Ks[0][r2 * AST + c1] = *(const h16x8*)(Qg + (size_t)(qa0 + r2) * DM + hc + c1);
        *(h16x8*)&Vs[0][r1 * AST + c1] = *(const h16x8*)(Qg + (size_t)(qb0 + r1) * DM + hc + c1);
        *(h16x8*)&Vs[0][r2 * AST + c1] = *(const h16x8*)(Qg + (size_t)(qb0 + r2) * DM + hc + c1);
    }
    // preload kt=0 K/V tile into regs
    h16x8 kv1 = *(const h16x8*)(Kg + (size_t)(r1) * DM + hc + c1);
    h16x8 kv2 = *(const h16x8*)(Kg + (size_t)(r2) * DM + hc + c1);
    h16x8 vv1 = *(const h16x8*)(Vt + (size_t)(hc + r1) * SEQ + c1);
    h16x8 vv2 = *(const h16x8*)(Vt + (size_t)(hc + r2) * SEQ + c1);

    __syncthreads();
    h16x8 qfA[2], qfB[2];
    qfA[0] = *(const h16x8*)&Ks[0][q_loc * AST + lq8];
    qfA[1] = *(const h16x8*)&Ks[0][q_loc * AST + 32 + lq8];
    qfB[0] = *(const h16x8*)&Vs[0][q_loc * AST + lq8];
    qfB[1] = *(const h16x8*)&Vs[0][q_loc * AST + 32 + lq8];
    __syncthreads();   // all Q-frag reads drained before iter-0 overwrites

    float mA = -1e30f, lA = 0.0f, mB = -1e30f, lB = 0.0f;
    f32x4 oA[4] = {}, oB[4] = {};
    h16* const psA = &Ps[0][(size_t)q_loc * AST];
    h16* const psB = &Ps[1][(size_t)q_loc * AST];

    for (int kt = 0; kt <= qB; ++kt) {
        h16* const Ksb = &Ks[kt & 1][0];
        h16* const Vsb = &Vs[kt & 1][0];
        *(h16x8*)&Ksb[r1 * AST + c1] = kv1;
        *(h16x8*)&Ksb[r2 * AST + c1] = kv2;
        *(h16x8*)&Vsb[r1 * AST + c1] = vv1;
        *(h16x8*)&Vsb[r2 * AST + c1] = vv2;
        __syncthreads();
        if (kt < qB) {   // prefetch next K/V tile (overlaps compute)
            const int k0n = (kt + 1) * 64;
            kv1 = *(const h16x8*)(Kg + (size_t)(k0n + r1) * DM + hc + c1);
            kv2 = *(const h16x8*)(Kg + (size_t)(k0n + r2) * DM + hc + c1);
            vv1 = *(const h16x8*)(Vt + (size_t)(hc + r1) * SEQ + k0n + c1);
            vv2 = *(const h16x8*)(Vt + (size_t)(hc + r2) * SEQ + k0n + c1);
        }
        const bool doA = (kt <= qA);

        // ---- S^T = K Q^T : K-frags read once, shared by both tiles ----
        f32x4 sA[4] = {}, sB[4] = {};
        #pragma unroll
        for (int kc = 0; kc < 2; ++kc)
            #pragma unroll
            for (int jj = 0; jj < 4; ++jj) {
                const h16x8 kf = *(const h16x8*)&Ksb[(jj * 16 + l15) * AST + kc * 32 + lq8];
                if (doA) sA[jj] = __builtin_amdgcn_mfma_f32_16x16x32_f16(kf, qfA[kc], sA[jj], 0, 0, 0);
                sB[jj] = __builtin_amdgcn_mfma_f32_16x16x32_f16(kf, qfB[kc], sB[jj], 0, 0, 0);
            }

        if (doA) tile_softmax(sA, mA, lA, oA, psA, kt == qA, q_loc, lq);
        tile_softmax(sB, mB, lB, oB, psB, kt == qB, q_loc, lq);

        // wave-local LDS round-trip for P^T (own 16-row band only)
        asm volatile("s_waitcnt lgkmcnt(0)" ::: "memory");
        h16x8 pfA[2], pfB[2];
        if (doA) {
            pfA[0] = *(const h16x8*)(psA + lq8);
            pfA[1] = *(const h16x8*)(psA + 32 + lq8);
        }
        pfB[0] = *(const h16x8*)(psB + lq8);
        pfB[1] = *(const h16x8*)(psB + 32 + lq8);

        // ---- O^T += V^T P^T : V-frags read once, shared by both tiles ----
        #pragma unroll
        for (int kc = 0; kc < 2; ++kc)
            #pragma unroll
            for (int jj = 0; jj < 4; ++jj) {
                const h16x8 vf = *(const h16x8*)&Vsb[(jj * 16 + l15) * AST + kc * 32 + lq8];
                if (doA) oA[jj] = __builtin_amdgcn_mfma_f32_16x16x32_f16(vf, pfA[kc], oA[jj], 0, 0, 0);
                oB[jj] = __builtin_amdgcn_mfma_f32_16x16x32_f16(vf, pfB[kc], oB[jj], 0, 0, 0);
            }
    }

    // ---- epilogue: O = O^T / l ----
    {
        const float il = 1.0f / lA;
        const size_t qg = (size_t)(qA * 64 + q_loc) * DM + hc;
        #pragma unroll
        for (int jj = 0; jj < 4; ++jj) {
            h16x4 ov = { (h16)(oA[jj][0] * il), (h16)(oA[jj][1] * il),
                         (h16)(oA[jj][2] * il), (h16)(oA[jj][3] * il) };
            *(h16x4*)(Og + qg + jj * 16 + lq * 4) = ov;
        }
    }
    {
        const float il = 1.0f / lB;
        const size_t qg = (size_t)(qB * 64 + q_loc) * DM + hc;
        #pragma unroll
        for (int jj = 0; jj < 4; ++jj) {
            h16x4 ov = { (h16)(oB[jj][0] * il), (h16)(oB[jj][1] * il),
                         (h16)(oB[jj][2] * il), (h16)(oB[jj][3] * il) };
            *(h16x4*)(Og + qg + jj * 16 + lq * 4) = ov;
        }
    }
}

// ---------------------------------------------------------------------------
extern "C" void kernel_launch(void* const* d_in, const int* in_sizes, int n_in,
                              void* d_out, int out_size, void* d_ws, size_t ws_size,
                              hipStream_t stream) {
    const float* x  = (const float*)d_in[0];
    const float* Wq = (const float*)d_in[1];
    const float* Wk = (const float*)d_in[2];
    const float* Wv = (const float*)d_in[3];
    const float* Wo = (const float*)d_in[4];
    float* out = (float*)d_out;

    const size_t SD = (size_t)SEQ * DM;   // 4M
    const size_t DD = (size_t)DM * DM;    // 1M

    h16* xh  = (h16*)d_ws;
    h16* wqh = xh + SD;
    h16* wkh = wqh + DD;
    h16* wvh = wkh + DD;
    h16* woh = wvh + DD;
    h16* Qh  = woh + DD;
    h16* Kh  = Qh + SD;
    h16* Vth = Kh + SD;     // transposed: [DM][SEQ]
    h16* AOh = Vth + SD;

    cvt_f32_f16<<<(int)(SD / 4 / 256), 256, 0, stream>>>(x,  xh,  (int)(SD / 4));
    cvt_f32_f16<<<(int)(DD / 4 / 256), 256, 0, stream>>>(Wq, wqh, (int)(DD / 4));
    cvt_f32_f16<<<(int)(DD / 4 / 256), 256, 0, stream>>>(Wk, wkh, (int)(DD / 4));
    cvt_f32_f16<<<(int)(DD / 4 / 256), 256, 0, stream>>>(Wv, wvh, (int)(DD / 4));
    cvt_f32_f16<<<(int)(DD / 4 / 256), 256, 0, stream>>>(Wo, woh, (int)(DD / 4));

    const dim3 blk(256);

    // Q pre-scaled by 1/sqrt(DH) * log2(e) for the exp2-domain softmax
    const float SCL = 0.125f * 1.44269504088896340736f;

    gemm_qkv<<<dim3(DM / 128, SEQ / 64, 3), blk, 0, stream>>>(
        xh, wqh, wkh, wvh, Qh, Kh, Vth, SCL);

    flash_attn_mfma<<<dim3(32, NH), blk, 0, stream>>>(Qh, Kh, Vth, AOh);

    gemm_out<<<dim3(DM / 128, SEQ / 64), blk, 0, stream>>>(AOh, woh, out);
}

// Round 8
// 237.194 us; speedup vs baseline: 2.4591x; 1.1107x over previous
//
#include <hip/hip_runtime.h>
#include <math.h>

#define SEQ 4096
#define DM  1024
#define NH  16
#define DH  64

typedef _Float16 h16;
typedef __attribute__((ext_vector_type(4))) _Float16 h16x4;
typedef __attribute__((ext_vector_type(8))) _Float16 h16x8;
typedef __attribute__((ext_vector_type(4))) float f32x4;

// async global->LDS, 16B per lane, dest = wave-uniform base + lane*16
__device__ __forceinline__ void gload_lds16(const h16* g, h16* l) {
    __builtin_amdgcn_global_load_lds(
        (const __attribute__((address_space(1))) void*)g,
        (__attribute__((address_space(3))) void*)l, 16, 0, 0);
}

// ---------------------------------------------------------------------------
// fp32 -> fp16 conversion, vectorized
// ---------------------------------------------------------------------------
__global__ __launch_bounds__(256) void cvt_f32_f16(const float* __restrict__ in,
                                                   h16* __restrict__ out, int n4) {
    const int i = blockIdx.x * 256 + threadIdx.x;
    if (i < n4) {
        const float4 v = ((const float4*)in)[i];
        h16x4 o = { (h16)v.x, (h16)v.y, (h16)v.z, (h16)v.w };
        ((h16x4*)out)[i] = o;
    }
}

// ---------------------------------------------------------------------------
// m97-style MFMA GEMM core: C[M][N] = A[M][K] @ B[N][K]^T, h16 in, fp32 acc.
// 128x128 tile, BK=32, 256 thr = 4 waves (2x2 of 64x64), 4x4 frags,
// 16 MFMA/wave-iter. Staging via global_load_lds width=16 into UNPADDED
// GST=32 layout (row = 64B -> lane-contiguous; b128 frag reads bank-balanced:
// start bank = 4*((4*l15+lq) mod 8), 8 lanes per group).
// ---------------------------------------------------------------------------
#define GT 32

// z = 0,1,2 -> Q (scaled), K, V^T outputs
__global__ __launch_bounds__(256) void gemm_qkv(const h16* __restrict__ xh,
                                                const h16* __restrict__ Wq,
                                                const h16* __restrict__ Wk,
                                                const h16* __restrict__ Wv,
                                                h16* __restrict__ Qh,
                                                h16* __restrict__ Kh,
                                                h16* __restrict__ Vth,
                                                float scl) {
    __shared__ h16 As[128 * GT];
    __shared__ h16 Bs[128 * GT];

    const int z    = blockIdx.z;
    const h16* B   = (z == 0) ? Wq : (z == 1) ? Wk : Wv;
    const int t    = threadIdx.x;
    const int lane = t & 63;
    const int w    = t >> 6;
    const int wm   = (w >> 1) * 64;
    const int wn   = (w & 1) * 64;
    const int l15  = lane & 15;
    const int lq   = lane >> 4;
    const int lq8  = lq * 8;
    const int m0   = blockIdx.y * 128;
    const int n0   = blockIdx.x * 128;
    const int K = DM, M = SEQ, N = DM;

    // staging map: wave w -> 16-row band; lane -> row w*16+(lane>>2), col (lane&3)*8
    const int srow = w * 16 + (lane >> 2);
    const int scol = (lane & 3) * 8;
    const h16* pa0 = xh + (size_t)(m0 + srow) * K + scol;
    const h16* pa1 = xh + (size_t)(m0 + 64 + srow) * K + scol;
    const h16* pb0 = B  + (size_t)(n0 + srow) * K + scol;
    const h16* pb1 = B  + (size_t)(n0 + 64 + srow) * K + scol;
    h16* const la0 = &As[w * 512];
    h16* const la1 = &As[2048 + w * 512];
    h16* const lb0 = &Bs[w * 512];
    h16* const lb1 = &Bs[2048 + w * 512];

    f32x4 acc[4][4] = {};

    for (int k0 = 0; k0 < K; k0 += 32) {
        __syncthreads();              // prior iter's frag reads done
        gload_lds16(pa0 + k0, la0);
        gload_lds16(pa1 + k0, la1);
        gload_lds16(pb0 + k0, lb0);
        gload_lds16(pb1 + k0, lb1);
        __syncthreads();              // drains vmcnt before barrier

        h16x8 af[4], bf[4];
        #pragma unroll
        for (int i = 0; i < 4; ++i)
            af[i] = *(const h16x8*)&As[(wm + i * 16 + l15) * GT + lq8];
        #pragma unroll
        for (int j = 0; j < 4; ++j)
            bf[j] = *(const h16x8*)&Bs[(wn + j * 16 + l15) * GT + lq8];
        #pragma unroll
        for (int i = 0; i < 4; ++i)
            #pragma unroll
            for (int j = 0; j < 4; ++j)
                acc[i][j] = __builtin_amdgcn_mfma_f32_16x16x32_f16(af[i], bf[j], acc[i][j], 0, 0, 0);
    }

    // C/D layout: col = lane&15, row = (lane>>4)*4 + r
    const int cr = wm + lq * 4;
    const int cc = wn + l15;
    if (z == 2) {   // V^T: h16 [N][M], vectorized along M
        #pragma unroll
        for (int i = 0; i < 4; ++i)
            #pragma unroll
            for (int j = 0; j < 4; ++j) {
                const int gm0 = m0 + cr + i * 16;
                const int gn  = n0 + cc + j * 16;
                h16x4 v = { (h16)acc[i][j][0], (h16)acc[i][j][1],
                            (h16)acc[i][j][2], (h16)acc[i][j][3] };
                *(h16x4*)(Vth + (size_t)gn * M + gm0) = v;
            }
    } else {
        h16* Og = (z == 0) ? Qh : Kh;
        const float e = (z == 0) ? scl : 1.0f;
        #pragma unroll
        for (int i = 0; i < 4; ++i)
            #pragma unroll
            for (int j = 0; j < 4; ++j)
                #pragma unroll
                for (int r = 0; r < 4; ++r) {
                    const int gm = m0 + cr + i * 16 + r;
                    const int gn = n0 + cc + j * 16;
                    Og[(size_t)gm * N + gn] = (h16)(acc[i][j][r] * e);
                }
    }
}

// out[M][N] (f32) = AO (h16) @ Wo^T (h16), same core
__global__ __launch_bounds__(256) void gemm_out(const h16* __restrict__ A,
                                                const h16* __restrict__ B,
                                                float* __restrict__ C) {
    __shared__ h16 As[128 * GT];
    __shared__ h16 Bs[128 * GT];

    const int t    = threadIdx.x;
    const int lane = t & 63;
    const int w    = t >> 6;
    const int wm   = (w >> 1) * 64;
    const int wn   = (w & 1) * 64;
    const int l15  = lane & 15;
    const int lq   = lane >> 4;
    const int lq8  = lq * 8;
    const int m0   = blockIdx.y * 128;
    const int n0   = blockIdx.x * 128;
    const int K = DM, N = DM;

    const int srow = w * 16 + (lane >> 2);
    const int scol = (lane & 3) * 8;
    const h16* pa0 = A + (size_t)(m0 + srow) * K + scol;
    const h16* pa1 = A + (size_t)(m0 + 64 + srow) * K + scol;
    const h16* pb0 = B + (size_t)(n0 + srow) * K + scol;
    const h16* pb1 = B + (size_t)(n0 + 64 + srow) * K + scol;
    h16* const la0 = &As[w * 512];
    h16* const la1 = &As[2048 + w * 512];
    h16* const lb0 = &Bs[w * 512];
    h16* const lb1 = &Bs[2048 + w * 512];

    f32x4 acc[4][4] = {};

    for (int k0 = 0; k0 < K; k0 += 32) {
        __syncthreads();
        gload_lds16(pa0 + k0, la0);
        gload_lds16(pa1 + k0, la1);
        gload_lds16(pb0 + k0, lb0);
        gload_lds16(pb1 + k0, lb1);
        __syncthreads();

        h16x8 af[4], bf[4];
        #pragma unroll
        for (int i = 0; i < 4; ++i)
            af[i] = *(const h16x8*)&As[(wm + i * 16 + l15) * GT + lq8];
        #pragma unroll
        for (int j = 0; j < 4; ++j)
            bf[j] = *(const h16x8*)&Bs[(wn + j * 16 + l15) * GT + lq8];
        #pragma unroll
        for (int i = 0; i < 4; ++i)
            #pragma unroll
            for (int j = 0; j < 4; ++j)
                acc[i][j] = __builtin_amdgcn_mfma_f32_16x16x32_f16(af[i], bf[j], acc[i][j], 0, 0, 0);
    }

    const int cr = wm + lq * 4;
    const int cc = wn + l15;
    #pragma unroll
    for (int i = 0; i < 4; ++i)
        #pragma unroll
        for (int j = 0; j < 4; ++j)
            #pragma unroll
            for (int r = 0; r < 4; ++r)
                C[(size_t)(m0 + cr + i * 16 + r) * N + n0 + cc + j * 16] = acc[i][j][r];
}

// ---------------------------------------------------------------------------
// MFMA flash attention (causal), S^T formulation, exp2 domain.
// Block = (pair {qA, 63-qA}, head). Single-buffered K/V + Ps[2] at AST=80
// -> 40 KB LDS; __launch_bounds__(256,3) -> VGPR cap 170 (no spill at ~156)
// -> 3 blocks/CU (12 waves/CU, +50% TLP vs round 7).
// K-loop split into phase 1 (kt<=qA: tiles A+B) and phase 2 (B only):
// uniform control flow per phase, independent A/B chains interleave.
// ---------------------------------------------------------------------------
#define AST 80

__device__ __forceinline__ void tile_softmax(f32x4 s[4], float& m_st, float& l_st,
                                             f32x4 o[4], h16* ps_row, bool diag,
                                             int q_loc, int lq) {
    if (diag) {   // block-uniform: only on the diagonal tile
        #pragma unroll
        for (int jj = 0; jj < 4; ++jj)
            #pragma unroll
            for (int r = 0; r < 4; ++r)
                if ((jj * 16 + lq * 4 + r) > q_loc) s[jj][r] = -1e30f;
    }
    float mx = m_st;
    #pragma unroll
    for (int jj = 0; jj < 4; ++jj)
        #pragma unroll
        for (int r = 0; r < 4; ++r)
            mx = fmaxf(mx, s[jj][r]);
    mx = fmaxf(mx, __shfl_xor(mx, 16, 64));
    mx = fmaxf(mx, __shfl_xor(mx, 32, 64));
    const float alpha = exp2f(m_st - mx);
    m_st = mx;
    float sum = 0.0f;
    #pragma unroll
    for (int jj = 0; jj < 4; ++jj) {
        const float p0 = exp2f(s[jj][0] - mx);
        const float p1 = exp2f(s[jj][1] - mx);
        const float p2 = exp2f(s[jj][2] - mx);
        const float p3 = exp2f(s[jj][3] - mx);
        sum += (p0 + p1) + (p2 + p3);
        h16x4 pk = { (h16)p0, (h16)p1, (h16)p2, (h16)p3 };
        *(h16x4*)(ps_row + jj * 16 + lq * 4) = pk;
    }
    sum += __shfl_xor(sum, 16, 64);
    sum += __shfl_xor(sum, 32, 64);
    l_st = l_st * alpha + sum;
    #pragma unroll
    for (int jj = 0; jj < 4; ++jj)
        #pragma unroll
        for (int r = 0; r < 4; ++r)
            o[jj][r] *= alpha;
}

__global__ __launch_bounds__(256, 3) void flash_attn_mfma(
        const h16* __restrict__ Qg, const h16* __restrict__ Kg,
        const h16* __restrict__ Vt, h16* __restrict__ Og) {
    __shared__ h16 Ks[64 * AST];      // [k_local][d]
    __shared__ h16 Vs[64 * AST];      // [d][k_local]
    __shared__ h16 Ps[2][64 * AST];   // [tile][q][k]

    const int qA   = blockIdx.x;          // 0..31
    const int qB   = 63 - qA;             // 32..63
    const int hh   = blockIdx.y;
    const int t    = threadIdx.x;
    const int lane = t & 63;
    const int w    = t >> 6;
    const int l15  = lane & 15;
    const int lq   = lane >> 4;
    const int lq8  = lq * 8;
    const int hc   = hh * DH;
    const int q_loc = w * 16 + l15;

    const int r1 = t >> 3;                // 0..31
    const int r2 = r1 + 32;
    const int c1 = (t & 7) * 8;

    // stage Q(A) into Ks, Q(B) into Vs (consumed before loop overwrites)
    {
        const int qa0 = qA * 64, qb0 = qB * 64;
        *(h16x8*)&Ks[r1 * AST + c1] = *(const h16x8*)(Qg + (size_t)(qa0 + r1) * DM + hc + c1);
        *(h16x8*)&Ks[r2 * AST + c1] = *(const h16x8*)(Qg + (size_t)(qa0 + r2) * DM + hc + c1);
        *(h16x8*)&Vs[r1 * AST + c1] = *(const h16x8*)(Qg + (size_t)(qb0 + r1) * DM + hc + c1);
        *(h16x8*)&Vs[r2 * AST + c1] = *(const h16x8*)(Qg + (size_t)(qb0 + r2) * DM + hc + c1);
    }
    // preload kt=0 K/V tile into regs
    h16x8 kv1 = *(const h16x8*)(Kg + (size_t)(r1) * DM + hc + c1);
    h16x8 kv2 = *(const h16x8*)(Kg + (size_t)(r2) * DM + hc + c1);
    h16x8 vv1 = *(const h16x8*)(Vt + (size_t)(hc + r1) * SEQ + c1);
    h16x8 vv2 = *(const h16x8*)(Vt + (size_t)(hc + r2) * SEQ + c1);

    __syncthreads();
    h16x8 qfA[2], qfB[2];
    qfA[0] = *(const h16x8*)&Ks[q_loc * AST + lq8];
    qfA[1] = *(const h16x8*)&Ks[q_loc * AST + 32 + lq8];
    qfB[0] = *(const h16x8*)&Vs[q_loc * AST + lq8];
    qfB[1] = *(const h16x8*)&Vs[q_loc * AST + 32 + lq8];

    float mA = -1e30f, lA = 0.0f, mB = -1e30f, lB = 0.0f;
    f32x4 oA[4] = {}, oB[4] = {};
    h16* const psA = &Ps[0][(size_t)q_loc * AST];
    h16* const psB = &Ps[1][(size_t)q_loc * AST];

    int kt = 0;
    // -------- phase 1: kt <= qA, both tiles active --------
    for (; kt <= qA; ++kt) {
        __syncthreads();
        *(h16x8*)&Ks[r1 * AST + c1] = kv1;
        *(h16x8*)&Ks[r2 * AST + c1] = kv2;
        *(h16x8*)&Vs[r1 * AST + c1] = vv1;
        *(h16x8*)&Vs[r2 * AST + c1] = vv2;
        __syncthreads();
        {   // prefetch (kt < qB always in phase 1)
            const int k0n = (kt + 1) * 64;
            kv1 = *(const h16x8*)(Kg + (size_t)(k0n + r1) * DM + hc + c1);
            kv2 = *(const h16x8*)(Kg + (size_t)(k0n + r2) * DM + hc + c1);
            vv1 = *(const h16x8*)(Vt + (size_t)(hc + r1) * SEQ + k0n + c1);
            vv2 = *(const h16x8*)(Vt + (size_t)(hc + r2) * SEQ + k0n + c1);
        }

        f32x4 sA[4] = {}, sB[4] = {};
        #pragma unroll
        for (int kc = 0; kc < 2; ++kc)
            #pragma unroll
            for (int jj = 0; jj < 4; ++jj) {
                const h16x8 kf = *(const h16x8*)&Ks[(jj * 16 + l15) * AST + kc * 32 + lq8];
                sA[jj] = __builtin_amdgcn_mfma_f32_16x16x32_f16(kf, qfA[kc], sA[jj], 0, 0, 0);
                sB[jj] = __builtin_amdgcn_mfma_f32_16x16x32_f16(kf, qfB[kc], sB[jj], 0, 0, 0);
            }

        tile_softmax(sA, mA, lA, oA, psA, kt == qA, q_loc, lq);
        tile_softmax(sB, mB, lB, oB, psB, false, q_loc, lq);

        asm volatile("s_waitcnt lgkmcnt(0)" ::: "memory");
        h16x8 pfA[2], pfB[2];
        pfA[0] = *(const h16x8*)(psA + lq8);
        pfA[1] = *(const h16x8*)(psA + 32 + lq8);
        pfB[0] = *(const h16x8*)(psB + lq8);
        pfB[1] = *(const h16x8*)(psB + 32 + lq8);

        #pragma unroll
        for (int kc = 0; kc < 2; ++kc)
            #pragma unroll
            for (int jj = 0; jj < 4; ++jj) {
                const h16x8 vf = *(const h16x8*)&Vs[(jj * 16 + l15) * AST + kc * 32 + lq8];
                oA[jj] = __builtin_amdgcn_mfma_f32_16x16x32_f16(vf, pfA[kc], oA[jj], 0, 0, 0);
                oB[jj] = __builtin_amdgcn_mfma_f32_16x16x32_f16(vf, pfB[kc], oB[jj], 0, 0, 0);
            }
    }
    // -------- phase 2: kt > qA, tile B only --------
    for (; kt <= qB; ++kt) {
        __syncthreads();
        *(h16x8*)&Ks[r1 * AST + c1] = kv1;
        *(h16x8*)&Ks[r2 * AST + c1] = kv2;
        *(h16x8*)&Vs[r1 * AST + c1] = vv1;
        *(h16x8*)&Vs[r2 * AST + c1] = vv2;
        __syncthreads();
        if (kt < qB) {
            const int k0n = (kt + 1) * 64;
            kv1 = *(const h16x8*)(Kg + (size_t)(k0n + r1) * DM + hc + c1);
            kv2 = *(const h16x8*)(Kg + (size_t)(k0n + r2) * DM + hc + c1);
            vv1 = *(const h16x8*)(Vt + (size_t)(hc + r1) * SEQ + k0n + c1);
            vv2 = *(const h16x8*)(Vt + (size_t)(hc + r2) * SEQ + k0n + c1);
        }

        f32x4 sB[4] = {};
        #pragma unroll
        for (int kc = 0; kc < 2; ++kc)
            #pragma unroll
            for (int jj = 0; jj < 4; ++jj) {
                const h16x8 kf = *(const h16x8*)&Ks[(jj * 16 + l15) * AST + kc * 32 + lq8];
                sB[jj] = __builtin_amdgcn_mfma_f32_16x16x32_f16(kf, qfB[kc], sB[jj], 0, 0, 0);
            }

        tile_softmax(sB, mB, lB, oB, psB, kt == qB, q_loc, lq);

        asm volatile("s_waitcnt lgkmcnt(0)" ::: "memory");
        h16x8 pfB[2];
        pfB[0] = *(const h16x8*)(psB + lq8);
        pfB[1] = *(const h16x8*)(psB + 32 + lq8);

        #pragma unroll
        for (int kc = 0; kc < 2; ++kc)
            #pragma unroll
            for (int jj = 0; jj < 4; ++jj) {
                const h16x8 vf = *(const h16x8*)&Vs[(jj * 16 + l15) * AST + kc * 32 + lq8];
                oB[jj] = __builtin_amdgcn_mfma_f32_16x16x32_f16(vf, pfB[kc], oB[jj], 0, 0, 0);
            }
    }

    // ---- epilogue: O = O^T / l ----
    {
        const float il = 1.0f / lA;
        const size_t qg = (size_t)(qA * 64 + q_loc) * DM + hc;
        #pragma unroll
        for (int jj = 0; jj < 4; ++jj) {
            h16x4 ov = { (h16)(oA[jj][0] * il), (h16)(oA[jj][1] * il),
                         (h16)(oA[jj][2] * il), (h16)(oA[jj][3] * il) };
            *(h16x4*)(Og + qg + jj * 16 + lq * 4) = ov;
        }
    }
    {
        const float il = 1.0f / lB;
        const size_t qg = (size_t)(qB * 64 + q_loc) * DM + hc;
        #pragma unroll
        for (int jj = 0; jj < 4; ++jj) {
            h16x4 ov = { (h16)(oB[jj][0] * il), (h16)(oB[jj][1] * il),
                         (h16)(oB[jj][2] * il), (h16)(oB[jj][3] * il) };
            *(h16x4*)(Og + qg + jj * 16 + lq * 4) = ov;
        }
    }
}

// ---------------------------------------------------------------------------
extern "C" void kernel_launch(void* const* d_in, const int* in_sizes, int n_in,
                              void* d_out, int out_size, void* d_ws, size_t ws_size,
                              hipStream_t stream) {
    const float* x  = (const float*)d_in[0];
    const float* Wq = (const float*)d_in[1];
    const float* Wk = (const float*)d_in[2];
    const float* Wv = (const float*)d_in[3];
    const float* Wo = (const float*)d_in[4];
    float* out = (float*)d_out;

    const size_t SD = (size_t)SEQ * DM;   // 4M
    const size_t DD = (size_t)DM * DM;    // 1M

    h16* xh  = (h16*)d_ws;
    h16* wqh = xh + SD;
    h16* wkh = wqh + DD;
    h16* wvh = wkh + DD;
    h16* woh = wvh + DD;
    h16* Qh  = woh + DD;
    h16* Kh  = Qh + SD;
    h16* Vth = Kh + SD;     // transposed: [DM][SEQ]
    h16* AOh = Vth + SD;

    cvt_f32_f16<<<(int)(SD / 4 / 256), 256, 0, stream>>>(x,  xh,  (int)(SD / 4));
    cvt_f32_f16<<<(int)(DD / 4 / 256), 256, 0, stream>>>(Wq, wqh, (int)(DD / 4));
    cvt_f32_f16<<<(int)(DD / 4 / 256), 256, 0, stream>>>(Wk, wkh, (int)(DD / 4));
    cvt_f32_f16<<<(int)(DD / 4 / 256), 256, 0, stream>>>(Wv, wvh, (int)(DD / 4));
    cvt_f32_f16<<<(int)(DD / 4 / 256), 256, 0, stream>>>(Wo, woh, (int)(DD / 4));

    const dim3 blk(256);

    // Q pre-scaled by 1/sqrt(DH) * log2(e) for the exp2-domain softmax
    const float SCL = 0.125f * 1.44269504088896340736f;

    gemm_qkv<<<dim3(DM / 128, SEQ / 128, 3), blk, 0, stream>>>(
        xh, wqh, wkh, wvh, Qh, Kh, Vth, SCL);

    flash_attn_mfma<<<dim3(32, NH), blk, 0, stream>>>(Qh, Kh, Vth, AOh);

    gemm_out<<<dim3(DM / 128, SEQ / 128), blk, 0, stream>>>(AOh, woh, out);
}

// Round 9
// 233.413 us; speedup vs baseline: 2.4989x; 1.0162x over previous
//
#include <hip/hip_runtime.h>
#include <math.h>

#define SEQ 4096
#define DM  1024
#define NH  16
#define DH  64

typedef _Float16 h16;
typedef __attribute__((ext_vector_type(4))) _Float16 h16x4;
typedef __attribute__((ext_vector_type(8))) _Float16 h16x8;
typedef __attribute__((ext_vector_type(4))) float f32x4;

// async global->LDS, 16B per lane, dest = wave-uniform base + lane*16
__device__ __forceinline__ void gload_lds16(const h16* g, h16* l) {
    __builtin_amdgcn_global_load_lds(
        (const __attribute__((address_space(1))) void*)g,
        (__attribute__((address_space(3))) void*)l, 16, 0, 0);
}

// ---------------------------------------------------------------------------
// Single fused fp32 -> fp16 conversion for x + all 4 weights.
// dst layout (contiguous in d_ws): [xh SD][wqh DD][wkh DD][wvh DD][woh DD].
// ---------------------------------------------------------------------------
__global__ __launch_bounds__(256) void cvt_all(const float* __restrict__ x,
                                               const float* __restrict__ wq,
                                               const float* __restrict__ wk,
                                               const float* __restrict__ wv,
                                               const float* __restrict__ wo,
                                               h16* __restrict__ dst) {
    const size_t SD4 = (size_t)SEQ * DM / 4;   // 1M float4s
    const size_t DD4 = (size_t)DM * DM / 4;    // 256K float4s
    const size_t i = (size_t)blockIdx.x * 256 + threadIdx.x;
    const float* src;
    size_t off;
    if (i < SD4) { src = x; off = i; }
    else {
        const size_t j = i - SD4;
        const int wsel = (int)(j >> 18);       // DD4 = 2^18
        off = j & (DD4 - 1);
        src = (wsel == 0) ? wq : (wsel == 1) ? wk : (wsel == 2) ? wv : wo;
    }
    const float4 v = ((const float4*)src)[off];
    h16x4 o = { (h16)v.x, (h16)v.y, (h16)v.z, (h16)v.w };
    ((h16x4*)dst)[i] = o;
}

// ---------------------------------------------------------------------------
// m97-style MFMA GEMM core: C[M][N] = A[M][K] @ B[N][K]^T, h16 in, fp32 acc.
// 128x128 tile, BK=64 as two 32-wide slabs (keeps conflict-free GT=32 layout,
// halves barrier count vs BK=32). Staging via global_load_lds width=16 into
// unpadded 64B rows (lane-contiguous). 256 thr = 4 waves (2x2 of 64x64),
// 4x4 frags, 32 MFMA per wave-iter. LDS 32 KB.
// ---------------------------------------------------------------------------
#define GT 32

// z = 0,1,2 -> Q (scaled), K, V^T outputs
__global__ __launch_bounds__(256) void gemm_qkv(const h16* __restrict__ xh,
                                                const h16* __restrict__ Wq,
                                                const h16* __restrict__ Wk,
                                                const h16* __restrict__ Wv,
                                                h16* __restrict__ Qh,
                                                h16* __restrict__ Kh,
                                                h16* __restrict__ Vth,
                                                float scl) {
    __shared__ h16 As[2][128 * GT];
    __shared__ h16 Bs[2][128 * GT];

    const int z    = blockIdx.z;
    const h16* B   = (z == 0) ? Wq : (z == 1) ? Wk : Wv;
    const int t    = threadIdx.x;
    const int lane = t & 63;
    const int w    = t >> 6;
    const int wm   = (w >> 1) * 64;
    const int wn   = (w & 1) * 64;
    const int l15  = lane & 15;
    const int lq   = lane >> 4;
    const int lq8  = lq * 8;
    const int m0   = blockIdx.y * 128;
    const int n0   = blockIdx.x * 128;
    const int K = DM, M = SEQ, N = DM;

    // staging: wave w -> 16-row band; lane -> row w*16+(lane>>2), col (lane&3)*8
    const int srow = w * 16 + (lane >> 2);
    const int scol = (lane & 3) * 8;
    const h16* pa0 = xh + (size_t)(m0 + srow) * K + scol;
    const h16* pa1 = xh + (size_t)(m0 + 64 + srow) * K + scol;
    const h16* pb0 = B  + (size_t)(n0 + srow) * K + scol;
    const h16* pb1 = B  + (size_t)(n0 + 64 + srow) * K + scol;

    f32x4 acc[4][4] = {};

    for (int k0 = 0; k0 < K; k0 += 64) {
        __syncthreads();              // prior iter's frag reads done
        #pragma unroll
        for (int s = 0; s < 2; ++s) {
            const int ko = k0 + s * 32;
            gload_lds16(pa0 + ko, &As[s][w * 512]);
            gload_lds16(pa1 + ko, &As[s][2048 + w * 512]);
            gload_lds16(pb0 + ko, &Bs[s][w * 512]);
            gload_lds16(pb1 + ko, &Bs[s][2048 + w * 512]);
        }
        __syncthreads();              // drains vmcnt before barrier

        #pragma unroll
        for (int s = 0; s < 2; ++s) {
            h16x8 af[4], bf[4];
            #pragma unroll
            for (int i = 0; i < 4; ++i)
                af[i] = *(const h16x8*)&As[s][(wm + i * 16 + l15) * GT + lq8];
            #pragma unroll
            for (int j = 0; j < 4; ++j)
                bf[j] = *(const h16x8*)&Bs[s][(wn + j * 16 + l15) * GT + lq8];
            #pragma unroll
            for (int i = 0; i < 4; ++i)
                #pragma unroll
                for (int j = 0; j < 4; ++j)
                    acc[i][j] = __builtin_amdgcn_mfma_f32_16x16x32_f16(af[i], bf[j], acc[i][j], 0, 0, 0);
        }
    }

    // C/D layout: col = lane&15, row = (lane>>4)*4 + r
    const int cr = wm + lq * 4;
    const int cc = wn + l15;
    if (z == 2) {   // V^T: h16 [N][M], vectorized along M
        #pragma unroll
        for (int i = 0; i < 4; ++i)
            #pragma unroll
            for (int j = 0; j < 4; ++j) {
                const int gm0 = m0 + cr + i * 16;
                const int gn  = n0 + cc + j * 16;
                h16x4 v = { (h16)acc[i][j][0], (h16)acc[i][j][1],
                            (h16)acc[i][j][2], (h16)acc[i][j][3] };
                *(h16x4*)(Vth + (size_t)gn * M + gm0) = v;
            }
    } else {
        h16* Og = (z == 0) ? Qh : Kh;
        const float e = (z == 0) ? scl : 1.0f;
        #pragma unroll
        for (int i = 0; i < 4; ++i)
            #pragma unroll
            for (int j = 0; j < 4; ++j)
                #pragma unroll
                for (int r = 0; r < 4; ++r) {
                    const int gm = m0 + cr + i * 16 + r;
                    const int gn = n0 + cc + j * 16;
                    Og[(size_t)gm * N + gn] = (h16)(acc[i][j][r] * e);
                }
    }
}

// out[M][N] (f32) = AO (h16) @ Wo^T (h16), same BK=64 core
__global__ __launch_bounds__(256) void gemm_out(const h16* __restrict__ A,
                                                const h16* __restrict__ B,
                                                float* __restrict__ C) {
    __shared__ h16 As[2][128 * GT];
    __shared__ h16 Bs[2][128 * GT];

    const int t    = threadIdx.x;
    const int lane = t & 63;
    const int w    = t >> 6;
    const int wm   = (w >> 1) * 64;
    const int wn   = (w & 1) * 64;
    const int l15  = lane & 15;
    const int lq   = lane >> 4;
    const int lq8  = lq * 8;
    const int m0   = blockIdx.y * 128;
    const int n0   = blockIdx.x * 128;
    const int K = DM, N = DM;

    const int srow = w * 16 + (lane >> 2);
    const int scol = (lane & 3) * 8;
    const h16* pa0 = A + (size_t)(m0 + srow) * K + scol;
    const h16* pa1 = A + (size_t)(m0 + 64 + srow) * K + scol;
    const h16* pb0 = B + (size_t)(n0 + srow) * K + scol;
    const h16* pb1 = B + (size_t)(n0 + 64 + srow) * K + scol;

    f32x4 acc[4][4] = {};

    for (int k0 = 0; k0 < K; k0 += 64) {
        __syncthreads();
        #pragma unroll
        for (int s = 0; s < 2; ++s) {
            const int ko = k0 + s * 32;
            gload_lds16(pa0 + ko, &As[s][w * 512]);
            gload_lds16(pa1 + ko, &As[s][2048 + w * 512]);
            gload_lds16(pb0 + ko, &Bs[s][w * 512]);
            gload_lds16(pb1 + ko, &Bs[s][2048 + w * 512]);
        }
        __syncthreads();

        #pragma unroll
        for (int s = 0; s < 2; ++s) {
            h16x8 af[4], bf[4];
            #pragma unroll
            for (int i = 0; i < 4; ++i)
                af[i] = *(const h16x8*)&As[s][(wm + i * 16 + l15) * GT + lq8];
            #pragma unroll
            for (int j = 0; j < 4; ++j)
                bf[j] = *(const h16x8*)&Bs[s][(wn + j * 16 + l15) * GT + lq8];
            #pragma unroll
            for (int i = 0; i < 4; ++i)
                #pragma unroll
                for (int j = 0; j < 4; ++j)
                    acc[i][j] = __builtin_amdgcn_mfma_f32_16x16x32_f16(af[i], bf[j], acc[i][j], 0, 0, 0);
        }
    }

    const int cr = wm + lq * 4;
    const int cc = wn + l15;
    #pragma unroll
    for (int i = 0; i < 4; ++i)
        #pragma unroll
        for (int j = 0; j < 4; ++j)
            #pragma unroll
            for (int r = 0; r < 4; ++r)
                C[(size_t)(m0 + cr + i * 16 + r) * N + n0 + cc + j * 16] = acc[i][j][r];
}

// ---------------------------------------------------------------------------
// MFMA flash attention (causal), S^T formulation, exp2 domain, UNPAIRED:
// one 64-row q-tile per block, grid (NH, 64) = 1024 blocks = 4 blocks/CU
// (2x the paired version's TLP). qt = 63 - blockIdx.y: heavy tiles dispatch
// first; oversubscription load-balances. LDS 30.7 KB; (256,3) avoids forced
// spills (round-6 lesson) while actual ~100 VGPR still allows 4 blocks/CU.
// ---------------------------------------------------------------------------
#define AST 80

__global__ __launch_bounds__(256, 3) void flash_attn_mfma(
        const h16* __restrict__ Qg, const h16* __restrict__ Kg,
        const h16* __restrict__ Vt, h16* __restrict__ Og) {
    __shared__ h16 Ks[64 * AST];   // [k_local][d]
    __shared__ h16 Vs[64 * AST];   // [d][k_local]
    __shared__ h16 Ps[64 * AST];   // [q][k]

    const int qt   = 63 - (int)blockIdx.y;
    const int hh   = blockIdx.x;
    const int t    = threadIdx.x;
    const int lane = t & 63;
    const int w    = t >> 6;
    const int l15  = lane & 15;
    const int lq   = lane >> 4;
    const int lq8  = lq * 8;
    const int hc   = hh * DH;
    const int q0   = qt * 64;
    const int q_loc = w * 16 + l15;

    const int r1 = t >> 3;             // 0..31
    const int r2 = r1 + 32;
    const int c1 = (t & 7) * 8;

    // stage Q into Ks (consumed into regs before loop overwrites)
    *(h16x8*)&Ks[r1 * AST + c1] = *(const h16x8*)(Qg + (size_t)(q0 + r1) * DM + hc + c1);
    *(h16x8*)&Ks[r2 * AST + c1] = *(const h16x8*)(Qg + (size_t)(q0 + r2) * DM + hc + c1);

    // preload kt=0 K/V tile into regs
    h16x8 kv1 = *(const h16x8*)(Kg + (size_t)(r1) * DM + hc + c1);
    h16x8 kv2 = *(const h16x8*)(Kg + (size_t)(r2) * DM + hc + c1);
    h16x8 vv1 = *(const h16x8*)(Vt + (size_t)(hc + r1) * SEQ + c1);
    h16x8 vv2 = *(const h16x8*)(Vt + (size_t)(hc + r2) * SEQ + c1);

    __syncthreads();
    h16x8 qf[2];
    qf[0] = *(const h16x8*)&Ks[q_loc * AST + lq8];
    qf[1] = *(const h16x8*)&Ks[q_loc * AST + 32 + lq8];

    float m_st = -1e30f, l_st = 0.0f;
    f32x4 o[4] = {};
    h16* const ps = &Ps[(size_t)q_loc * AST];

    for (int kt = 0; kt <= qt; ++kt) {
        __syncthreads();   // prior frag/qf reads drained (waitcnt before barrier)
        *(h16x8*)&Ks[r1 * AST + c1] = kv1;
        *(h16x8*)&Ks[r2 * AST + c1] = kv2;
        *(h16x8*)&Vs[r1 * AST + c1] = vv1;
        *(h16x8*)&Vs[r2 * AST + c1] = vv2;
        __syncthreads();
        if (kt < qt) {     // prefetch next K/V tile (overlaps compute)
            const int k0n = (kt + 1) * 64;
            kv1 = *(const h16x8*)(Kg + (size_t)(k0n + r1) * DM + hc + c1);
            kv2 = *(const h16x8*)(Kg + (size_t)(k0n + r2) * DM + hc + c1);
            vv1 = *(const h16x8*)(Vt + (size_t)(hc + r1) * SEQ + k0n + c1);
            vv2 = *(const h16x8*)(Vt + (size_t)(hc + r2) * SEQ + k0n + c1);
        }

        // ---- S^T = K Q^T (one q per lane in C-layout cols) ----
        f32x4 s[4] = {};
        #pragma unroll
        for (int kc = 0; kc < 2; ++kc)
            #pragma unroll
            for (int jj = 0; jj < 4; ++jj) {
                const h16x8 kf = *(const h16x8*)&Ks[(jj * 16 + l15) * AST + kc * 32 + lq8];
                s[jj] = __builtin_amdgcn_mfma_f32_16x16x32_f16(kf, qf[kc], s[jj], 0, 0, 0);
            }

        // ---- online softmax: in-lane over 16 k + 2 shfls ----
        if (kt == qt) {   // block-uniform: diagonal tile only
            #pragma unroll
            for (int jj = 0; jj < 4; ++jj)
                #pragma unroll
                for (int r = 0; r < 4; ++r)
                    if ((jj * 16 + lq * 4 + r) > q_loc) s[jj][r] = -1e30f;
        }
        float mx = m_st;
        #pragma unroll
        for (int jj = 0; jj < 4; ++jj)
            #pragma unroll
            for (int r = 0; r < 4; ++r)
                mx = fmaxf(mx, s[jj][r]);
        mx = fmaxf(mx, __shfl_xor(mx, 16, 64));
        mx = fmaxf(mx, __shfl_xor(mx, 32, 64));
        const float alpha = exp2f(m_st - mx);
        m_st = mx;
        float sum = 0.0f;
        #pragma unroll
        for (int jj = 0; jj < 4; ++jj) {
            const float p0 = exp2f(s[jj][0] - mx);
            const float p1 = exp2f(s[jj][1] - mx);
            const float p2 = exp2f(s[jj][2] - mx);
            const float p3 = exp2f(s[jj][3] - mx);
            sum += (p0 + p1) + (p2 + p3);
            h16x4 pk = { (h16)p0, (h16)p1, (h16)p2, (h16)p3 };
            *(h16x4*)(ps + jj * 16 + lq * 4) = pk;
        }
        sum += __shfl_xor(sum, 16, 64);
        sum += __shfl_xor(sum, 32, 64);
        l_st = l_st * alpha + sum;
        #pragma unroll
        for (int jj = 0; jj < 4; ++jj)
            #pragma unroll
            for (int r = 0; r < 4; ++r)
                o[jj][r] *= alpha;

        // wave-local LDS round-trip for P^T (own 16-row band only)
        asm volatile("s_waitcnt lgkmcnt(0)" ::: "memory");
        h16x8 pf[2];
        pf[0] = *(const h16x8*)(ps + lq8);
        pf[1] = *(const h16x8*)(ps + 32 + lq8);

        // ---- O^T += V^T P^T ----
        #pragma unroll
        for (int kc = 0; kc < 2; ++kc)
            #pragma unroll
            for (int jj = 0; jj < 4; ++jj) {
                const h16x8 vf = *(const h16x8*)&Vs[(jj * 16 + l15) * AST + kc * 32 + lq8];
                o[jj] = __builtin_amdgcn_mfma_f32_16x16x32_f16(vf, pf[kc], o[jj], 0, 0, 0);
            }
    }

    // ---- epilogue: O = O^T / l ----
    const float il = 1.0f / l_st;
    const size_t qg = (size_t)(q0 + q_loc) * DM + hc;
    #pragma unroll
    for (int jj = 0; jj < 4; ++jj) {
        h16x4 ov = { (h16)(o[jj][0] * il), (h16)(o[jj][1] * il),
                     (h16)(o[jj][2] * il), (h16)(o[jj][3] * il) };
        *(h16x4*)(Og + qg + jj * 16 + lq * 4) = ov;
    }
}

// ---------------------------------------------------------------------------
extern "C" void kernel_launch(void* const* d_in, const int* in_sizes, int n_in,
                              void* d_out, int out_size, void* d_ws, size_t ws_size,
                              hipStream_t stream) {
    const float* x  = (const float*)d_in[0];
    const float* Wq = (const float*)d_in[1];
    const float* Wk = (const float*)d_in[2];
    const float* Wv = (const float*)d_in[3];
    const float* Wo = (const float*)d_in[4];
    float* out = (float*)d_out;

    const size_t SD = (size_t)SEQ * DM;   // 4M
    const size_t DD = (size_t)DM * DM;    // 1M

    h16* xh  = (h16*)d_ws;                // cvt_all relies on this contiguity
    h16* wqh = xh + SD;
    h16* wkh = wqh + DD;
    h16* wvh = wkh + DD;
    h16* woh = wvh + DD;
    h16* Qh  = woh + DD;
    h16* Kh  = Qh + SD;
    h16* Vth = Kh + SD;     // transposed: [DM][SEQ]
    h16* AOh = Vth + SD;

    const dim3 blk(256);

    cvt_all<<<(int)((SD + 4 * DD) / 4 / 256), blk, 0, stream>>>(x, Wq, Wk, Wv, Wo, xh);

    // Q pre-scaled by 1/sqrt(DH) * log2(e) for the exp2-domain softmax
    const float SCL = 0.125f * 1.44269504088896340736f;

    gemm_qkv<<<dim3(DM / 128, SEQ / 128, 3), blk, 0, stream>>>(
        xh, wqh, wkh, wvh, Qh, Kh, Vth, SCL);

    flash_attn_mfma<<<dim3(NH, 64), blk, 0, stream>>>(Qh, Kh, Vth, AOh);

    gemm_out<<<dim3(DM / 128, SEQ / 128), blk, 0, stream>>>(AOh, woh, out);
}